// Round 6
// baseline (752.137 us; speedup 1.0000x reference)
//
#include <hip/hip_runtime.h>

#define NEGF (-1e30f)

constexpr int S = 512;
constexpr int L = 32;
constexpr int SL1 = (S + 1) * L;      // seg offset step per frame (element units)
constexpr int SLN = S * L;            // step per j
constexpr int SSL = S * S * L;        // per-batch seg element count (bounds clamp)
constexpr int RSTR = 33;              // ring row stride (floats)
constexpr int RROWS = 128;            // ring rows; beta[p] lives at row (p+1)&127
constexpr int RWRAP = RROWS * RSTR;   // 4224
constexpr int SPIN_CAP = 1 << 20;     // bounded spin: deadlock -> visible failure

// R11 = R10 with two fixes:
//  (a) #pragma unroll 1 on the steady-state chain loop (R10's constant-trip
//      loop around BODY16 invited full unroll -> ~480 CHAIN expansions ->
//      compile blowup = the likely "container failed twice").
//  (b) lag j-split h=0: j=16..40, h=1: j=41..65 (pad term masked) so the beta
//      window index k = q + 24 - i is compile-time for BOTH halves -> bR[28]
//      stays in registers (R10's h-dependent koff made it lane-divergent
//      runtime indexing -> scratch, rule #20).
// Architecture (unchanged): chain wave = serial core, j=1..15 via 16-slot
// static register ring (zero shift movs), one LDS round trip (ubuf) per frame,
// defer-max normalizer, poll/pub once per 4 frames.  Lag waves = j>=16
// partials, 4-frame batches stride 12, gate chain >= F-13, beta window read
// once per batch into registers.

template <int CTRL>
__device__ __forceinline__ float dppf(float x) {
    return __builtin_bit_cast(float,
        __builtin_amdgcn_update_dpp(0, __builtin_bit_cast(int, x),
                                    CTRL, 0xf, 0xf, true));
}
// max over each 32-lane half (all lanes get result); off critical path only.
#define RED32_MAX(v) do { v = fmaxf(v, dppf<0xB1>(v));                      \
                          v = fmaxf(v, dppf<0x4E>(v));                      \
                          v = fmaxf(v, dppf<0x141>(v));                     \
                          v = fmaxf(v, dppf<0x140>(v));                     \
                          v = fmaxf(v, __shfl_xor(v, 16)); } while (0)

// ---------------------------------------------------------------- chain macro
// U: compile-time frame-within-body (0..15); frame ff = fbase + U.
#define CHAIN(U, SBUF, DOPOLL, DOPUB) do {                                  \
    const int ff = fbase + (U);                                             \
    /* off-path: j=2..15 terms from static register ring */                 \
    float tj[14];                                                           \
    _Pragma("unroll")                                                       \
    for (int i = 0; i < 14; ++i)                                            \
        tj[i] = bH[((U) + 14 - i) & 15] +                                   \
                fmaf(SBUF[i + 1], (float)(i + 2), dgc[i]);                  \
    float Mp = fmaxf(                                                       \
        fmaxf(fmaxf(fmaxf(tj[0],tj[1]),fmaxf(tj[2],tj[3])),                 \
              fmaxf(fmaxf(tj[4],tj[5]),fmaxf(tj[6],tj[7]))),                \
        fmaxf(fmaxf(fmaxf(tj[8],tj[9]),fmaxf(tj[10],tj[11])),               \
              fmaxf(fmaxf(tj[12],tj[13]), pp1.x)));                         \
    float exv[14];                                                          \
    _Pragma("unroll")                                                       \
    for (int i = 0; i < 14; ++i) exv[i] = __expf(tj[i] - Mp);               \
    const float exP = pp1.y * __expf(pp1.x - Mp);                           \
    const float Sp =                                                        \
        (((exv[0]+exv[1])+(exv[2]+exv[3]))+((exv[4]+exv[5])+(exv[6]+exv[7])))\
      + (((exv[8]+exv[9])+(exv[10]+exv[11]))+((exv[12]+exv[13])+exP));      \
    float mxn = Ma;                                                         \
    RED32_MAX(mxn);                    /* max alpha[ff], used NEXT frame */ \
    /* on-path: u broadcast -> dot -> beta[ff] */                           \
    const float uu = Sa * __expf(Ma - mx);                                  \
    ubuf[c] = uu;                      /* both halves write identical data */\
    const float4 u0 = *(const float4*)&ubuf[0];                             \
    const float4 u1 = *(const float4*)&ubuf[4];                             \
    const float4 u2 = *(const float4*)&ubuf[8];                             \
    const float4 u3 = *(const float4*)&ubuf[12];                            \
    const float4 u4 = *(const float4*)&ubuf[16];                            \
    const float4 u5 = *(const float4*)&ubuf[20];                            \
    const float4 u6 = *(const float4*)&ubuf[24];                            \
    const float4 u7 = *(const float4*)&ubuf[28];                            \
    float d0 = u0.x * E[0];                                                 \
    d0 = fmaf(u0.y, E[1], d0);  d0 = fmaf(u0.z, E[2], d0);                  \
    d0 = fmaf(u0.w, E[3], d0);  d0 = fmaf(u1.x, E[4], d0);                  \
    d0 = fmaf(u1.y, E[5], d0);  d0 = fmaf(u1.z, E[6], d0);                  \
    d0 = fmaf(u1.w, E[7], d0);                                              \
    float d1 = u2.x * E[8];                                                 \
    d1 = fmaf(u2.y, E[9],  d1); d1 = fmaf(u2.z, E[10], d1);                 \
    d1 = fmaf(u2.w, E[11], d1); d1 = fmaf(u3.x, E[12], d1);                 \
    d1 = fmaf(u3.y, E[13], d1); d1 = fmaf(u3.z, E[14], d1);                 \
    d1 = fmaf(u3.w, E[15], d1);                                             \
    float d2 = u4.x * E[16];                                                \
    d2 = fmaf(u4.y, E[17], d2); d2 = fmaf(u4.z, E[18], d2);                 \
    d2 = fmaf(u4.w, E[19], d2); d2 = fmaf(u5.x, E[20], d2);                 \
    d2 = fmaf(u5.y, E[21], d2); d2 = fmaf(u5.z, E[22], d2);                 \
    d2 = fmaf(u5.w, E[23], d2);                                             \
    float d3 = u6.x * E[24];                                                \
    d3 = fmaf(u6.y, E[25], d3); d3 = fmaf(u6.z, E[26], d3);                 \
    d3 = fmaf(u6.w, E[27], d3); d3 = fmaf(u7.x, E[28], d3);                 \
    d3 = fmaf(u7.y, E[29], d3); d3 = fmaf(u7.z, E[30], d3);                 \
    d3 = fmaf(u7.w, E[31], d3);                                             \
    const float dot = (d0 + d1) + (d2 + d3);                                \
    const float bb = mx + __logf(dot);                                      \
    ring[wadr] = bb;                   /* both halves, identical data */    \
    wadr += RSTR; if (wadr >= RWRAP) wadr -= RWRAP;                         \
    /* merge -> alpha[ff+1] */                                              \
    const float t1 = bb + SBUF[0];                                          \
    const float Man = fmaxf(Mp, t1);                                        \
    Sa = fmaf(Sp, __expf(Mp - Man), __expf(t1 - Man));                      \
    Ma = Man;                                                               \
    mx = mxn;                                                               \
    bH[(U) & 15] = bb;                                                      \
    if (DOPUB) {                                                            \
        asm volatile("s_waitcnt lgkmcnt(0)" ::: "memory");                  \
        if (t == 0) cntv[3] = ff;                                           \
    }                                                                       \
    if (DOPOLL) {                                                           \
        const int Fb = ff + 3;                                              \
        if (Fb <= 508) {                                                    \
            volatile int* cw = &cntv[(Fb >> 2) % 3];                        \
            int zz = 0;                                                     \
            while (*cw < Fb && ++zz < SPIN_CAP) {}                          \
            __builtin_amdgcn_fence(__ATOMIC_ACQUIRE, "workgroup", "local"); \
        }                                                                   \
    }                                                                       \
    pp1 = pp2;                                                              \
    pp2 = part[(ff + 3) & 31][c];                                           \
    /* refill SBUF with seg col e = ff+5 (used at frame ff+4); clamped */   \
    _Pragma("unroll")                                                       \
    for (int i = 0; i < 15; ++i) {                                          \
        int o = offv[i];                                                    \
        o = (o < (int)c || o >= SSL) ? (int)c : o;                          \
        SBUF[i] = segB[o];                                                  \
        offv[i] += SL1;                                                     \
    }                                                                       \
} while (0)

#define BODY16() do {                                                       \
    CHAIN(0, sA, 0,0); CHAIN(1, sB, 1,0);                                   \
    CHAIN(2, sC, 0,0); CHAIN(3, sD, 0,1);                                   \
    CHAIN(4, sA, 0,0); CHAIN(5, sB, 1,0);                                   \
    CHAIN(6, sC, 0,0); CHAIN(7, sD, 0,1);                                   \
    CHAIN(8, sA, 0,0); CHAIN(9, sB, 1,0);                                   \
    CHAIN(10,sC, 0,0); CHAIN(11,sD, 0,1);                                   \
    CHAIN(12,sA, 0,0); CHAIN(13,sB, 1,0);                                   \
    CHAIN(14,sC, 0,0); CHAIN(15,sD, 0,1);                                   \
} while (0)

// ------------------------------------------------------------------ lag macros
#define LLOAD(BUF) do {                                                     \
    _Pragma("unroll")                                                       \
    for (int i = 0; i < 25; ++i) {                                          \
        int o = offs[i];                                                    \
        o = (o < (int)c || o >= SSL) ? (int)c : o;                          \
        BUF[i] = segB[o];                                                   \
        offs[i] += SL1;                                                     \
    }                                                                       \
} while (0)

// per-batch beta window -> registers (28 ds_reads / batch / wave)
#define LOADBR() do {                                                       \
    _Pragma("unroll")                                                       \
    for (int k = 0; k < 28; ++k) {                                          \
        int a = rbase + k * RSTR;                                           \
        if (a >= RWRAP) a -= RWRAP;                                         \
        bR[k] = ring[a];                                                    \
    }                                                                       \
} while (0)

// bR index k = q + 24 - i : compile-time for BOTH halves (R11 fix b).
#define LF(q_, BUF, MSK) do {                                               \
    const int ff = F + (q_);                                                \
    float tt[25];                                                           \
    _Pragma("unroll")                                                       \
    for (int i = 0; i < 25; ++i) {                                          \
        const float tv = bR[(q_) + 24 - i] + fmaf(BUF[i], jfv[i], dgv[i]);  \
        bool vld = (i < nt);                                                \
        if (MSK) vld = vld && (jlo + i <= ff + 1);                          \
        tt[i] = vld ? tv : NEGF;                                            \
    }                                                                       \
    float m = fmaxf(                                                        \
        fmaxf(fmaxf(fmaxf(tt[0],tt[1]),fmaxf(tt[2],tt[3])),                 \
              fmaxf(fmaxf(tt[4],tt[5]),fmaxf(tt[6],tt[7]))),                \
        fmaxf(fmaxf(fmaxf(tt[8],tt[9]),fmaxf(tt[10],tt[11])),               \
              fmaxf(fmaxf(tt[12],tt[13]),fmaxf(tt[14],tt[15]))));           \
    m = fmaxf(m, fmaxf(                                                     \
        fmaxf(fmaxf(tt[16],tt[17]),fmaxf(tt[18],tt[19])),                   \
        fmaxf(fmaxf(tt[20],tt[21]),fmaxf(tt[22],tt[23]))));                 \
    m = fmaxf(m, tt[24]);                                                   \
    float e_[25];                                                           \
    _Pragma("unroll")                                                       \
    for (int i = 0; i < 25; ++i) e_[i] = __expf(tt[i] - m);                 \
    const float s =                                                         \
        ((((e_[0]+e_[1])+(e_[2]+e_[3]))+((e_[4]+e_[5])+(e_[6]+e_[7])))      \
       + (((e_[8]+e_[9])+(e_[10]+e_[11]))+((e_[12]+e_[13])+(e_[14]+e_[15]))))\
      + ((((e_[16]+e_[17])+(e_[18]+e_[19]))+((e_[20]+e_[21])+(e_[22]+e_[23])))\
       + e_[24]);                                                           \
    const float m2 = __shfl_xor(m, 32);                                     \
    const float s2 = __shfl_xor(s, 32);                                     \
    const float Mw = fmaxf(m, m2);                                          \
    const float Sw = fmaf(s, __expf(m - Mw), s2 * __expf(m2 - Mw));         \
    if (h == 0) part[ff & 31][c] = make_float2(Mw, Sw);                     \
} while (0)

__launch_bounds__(256, 1)
__global__ void semicrf_fwd(const float* __restrict__ seg,
                            const float* __restrict__ trans,
                            float* __restrict__ out)
{
    const int t  = threadIdx.x;
    const int b  = blockIdx.x;
    const int c  = t & 31;
    const int h  = (t >> 5) & 1;
    const int wv = t >> 6;

    __shared__ float ring[RROWS * RSTR];        // log-beta; row (p+1)&127
    __shared__ float2 part[32][32];             // lag (M,S) partials, slot f&31
    __shared__ __align__(16) float ubuf[32];    // chain matvec broadcast
    __shared__ int cnt_s[4];                    // 0..2 lag batch done, 3 chain done

    for (int i = t; i < 32 * 32; i += 256)
        ((float2*)part)[i] = make_float2(NEGF, 0.f);
    if (t < 32) ring[t] = 0.f;                  // row 0 = beta[-1] = 0
    if (t < 4)  cnt_s[t] = -1;
    __syncthreads();                            // only barrier in the kernel

    const float* segB = seg + (size_t)b * S * S * L;
    volatile int* cntv = cnt_s;

    if (wv == 0) {
        // -------------------- chain wave --------------------
        __builtin_amdgcn_s_setprio(1);
        float E[32];
#pragma unroll
        for (int i = 0; i < 32; ++i) E[i] = __expf(trans[i * 32 + c]);
        const float diag_c = trans[c * 33];
        float dgc[14];
#pragma unroll
        for (int i = 0; i < 14; ++i) dgc[i] = diag_c * (float)(i + 1);

        // static register ring: bH[g & 15] = beta[g]; init beta[-1]=0 @slot 15
        float bH[16];
#pragma unroll
        for (int i = 0; i < 16; ++i) bH[i] = NEGF;
        bH[15] = 0.f;

        // seg buffers: frame ff uses buffer (ff&3) holding col ff+1
        float sA[15], sB[15], sC[15], sD[15];
        int offv[15];
#pragma unroll
        for (int i = 0; i < 15; ++i) {
            int o1 = 1 * SL1 - i * SLN + (int)c;   // col 1
            int o2 = 2 * SL1 - i * SLN + (int)c;   // col 2
            int o3 = 3 * SL1 - i * SLN + (int)c;   // col 3
            int o4 = 4 * SL1 - i * SLN + (int)c;   // col 4
            o1 = o1 < (int)c ? (int)c : o1;
            o2 = o2 < (int)c ? (int)c : o2;
            o3 = o3 < (int)c ? (int)c : o3;
            o4 = o4 < (int)c ? (int)c : o4;
            sA[i] = segB[o1];
            sB[i] = segB[o2];
            sC[i] = segB[o3];
            sD[i] = segB[o4];
            offv[i] = 5 * SL1 - i * SLN + (int)c;  // next load: col 5
        }

        float Ma = segB[c];                     // alpha[0] as (max,sum)
        float Sa = 1.f;
        float mx = Ma;
        RED32_MAX(mx);                          // exact normalizer for frame 0
        int wadr = RSTR + (int)c;               // beta[0] -> row 1

        // wait batch 0, prime pp1=partial(1), pp2=partial(2)
        {
            volatile int* cw = &cntv[0];
            int zz = 0;
            while (*cw < 0 && ++zz < SPIN_CAP) {}
            __builtin_amdgcn_fence(__ATOMIC_ACQUIRE, "workgroup", "local");
        }
        float2 pp1 = part[1][c];
        float2 pp2 = part[2][c];

        int fbase = 0;
        BODY16();                               // frames 0..15
#pragma unroll 1
        for (fbase = 16; fbase <= 480; fbase += 16)
            BODY16();                           // frames 16..495 (NOT unrolled)
        fbase = 496;                            // frames 496..510
        CHAIN(0, sA, 0,0); CHAIN(1, sB, 1,0);
        CHAIN(2, sC, 0,0); CHAIN(3, sD, 0,1);
        CHAIN(4, sA, 0,0); CHAIN(5, sB, 1,0);
        CHAIN(6, sC, 0,0); CHAIN(7, sD, 0,1);
        CHAIN(8, sA, 0,0); CHAIN(9, sB, 1,0);
        CHAIN(10,sC, 0,0); CHAIN(11,sD, 0,1);
        CHAIN(12,sA, 0,0); CHAIN(13,sB, 1,0);
        CHAIN(14,sC, 0,0);

        // log_z[b] = LSE_c ( Ma + log Sa ); halves duplicate -> xor <= 16
        float m = Ma + __logf(Sa);
        float ss = 1.f;
#pragma unroll
        for (int mk = 1; mk <= 16; mk <<= 1) {
            const float m2 = __shfl_xor(m, mk);
            const float s2 = __shfl_xor(ss, mk);
            const float mn = fmaxf(m, m2);
            ss = ss * __expf(m - mn) + s2 * __expf(m2 - mn);
            m  = mn;
        }
        if (t == 0) out[b] = m + __logf(ss);
    } else {
        // -------------- lag waves: j=16..40 (h=0) / 41..65-pad (h=1) --------
        const int wl  = wv - 1;                 // 0,1,2
        const int jlo = h ? 41 : 16;
        const int nt  = h ? 24 : 25;            // valid terms this half
        const int jhi = h ? 65 : 40;            // window top (incl. pad)
        const float diag_c = trans[c * 33];

        float jfv[25], dgv[25];
        int offs[25];
        const int F0 = 4 * wl;
#pragma unroll
        for (int i = 0; i < 25; ++i) {
            const int jj = jlo + i;             // pad term (h=1,i=24) masked
            jfv[i] = (float)jj;
            dgv[i] = diag_c * (float)(jj - 1);
            offs[i] = F0 * SL1 - (jj - 1) * SLN + (int)c;
        }
        // beta window base: pmin = F - jhi; row (pmin+1)&127
        int rbase = (((F0 - jhi + 1) & 127) * RSTR) + (int)c;

        float bufA[25], bufB[25], bR[28];
        int cdv = -1;
        int F = F0;
        LLOAD(bufA);                            // frame F
        LLOAD(bufB);                            // frame F+1
        while (F <= 508) {
            if (F >= 16) {
                const int need = F - 13;
                int zz = 0;
                while (cdv < need && ++zz < SPIN_CAP) {
                    __builtin_amdgcn_s_sleep(1); cdv = cntv[3];
                }
                __builtin_amdgcn_fence(__ATOMIC_ACQUIRE, "workgroup", "local");
            }
            LOADBR();                           // 28-row beta window -> regs
            if (F <= 60) {
                LF(0, bufA, 1); LLOAD(bufA);    // loads F+2
                LF(1, bufB, 1); LLOAD(bufB);    // loads F+3
                LF(2, bufA, 1);
                LF(3, bufB, 1);
            } else {
                LF(0, bufA, 0); LLOAD(bufA);
                LF(1, bufB, 0); LLOAD(bufB);
                LF(2, bufA, 0);
                LF(3, bufB, 0);
            }
            asm volatile("s_waitcnt lgkmcnt(0)" ::: "memory");
            if ((t & 63) == 0) cntv[wl] = F;
            // advance to next batch (F+12): offs currently at F+4
#pragma unroll
            for (int i = 0; i < 25; ++i) offs[i] += 8 * SL1;
            rbase += 12 * RSTR; if (rbase >= RWRAP) rbase -= RWRAP;
            F += 12;
            if (F <= 508) { LLOAD(bufA); LLOAD(bufB); }
        }
    }
}

extern "C" void kernel_launch(void* const* d_in, const int* in_sizes, int n_in,
                              void* d_out, int out_size, void* d_ws, size_t ws_size,
                              hipStream_t stream) {
    const float* seg   = (const float*)d_in[0];   // [8, 512, 512, 32] fp32
    const float* trans = (const float*)d_in[1];   // [32, 32] fp32
    float* out = (float*)d_out;                   // [8] fp32
    hipLaunchKernelGGL(semicrf_fwd, dim3(8), dim3(256), 0, stream,
                       seg, trans, out);
}

// Round 7
// 648.648 us; speedup vs baseline: 1.1595x; 1.1595x over previous
//
#include <hip/hip_runtime.h>

#define NEGF (-1e30f)

constexpr int S = 512;
constexpr int L = 32;
constexpr int SL1 = (S + 1) * L;      // seg offset step per frame (element units)
constexpr int SLN = S * L;            // step per j
constexpr int SSL = S * S * L;        // per-batch seg element count (bounds clamp)
constexpr int RSTR = 33;              // ring row stride (floats)
constexpr int RROWS = 128;            // ring rows; beta[p] lives at row (p+1)&127
constexpr int RWRAP = RROWS * RSTR;   // 4224
constexpr int SPIN_CAP = 1 << 20;     // bounded spin: deadlock -> visible failure

// R12 = R9's chain (proven 370us, absmax 0) + batched-lag-reads only.
//   alpha[f][c] = LSE_{j=1..min(64,f+1)} beta[f-j][c] + j*seg[f-j+1,f,c] + (j-1)*diag[c]
//   beta[p][c]  = LSE_prev alpha[p][prev] + T[prev][c],  beta[-1]=0 (ring row 0)
// Chain wave: j=1..15 from a 14-deep shift register history (R9 exact: small
//   4-frame loop body, ~600 inst — R11's 16-frame inlined body regressed 370->470,
//   suspected I-fetch pressure on the serial loop; its static-ring read index
//   was also off by one frame -> absmax=32).
// Lag waves (the ONLY change vs R9): j-split h=0: j=16..40, h=1: j=41..65
//   (pad masked) so the per-batch beta window bR[28] uses the SAME compile-time
//   index k = q+24-i for both halves (register-resident, rule #20 safe).
//   28 ds_reads/batch replaces R9's 100 per frame-group -> DS-pipe traffic
//   ~-70%, testing the theory that lag LDS bursts queue the chain's serial
//   ubuf round-trip behind them.

template <int CTRL>
__device__ __forceinline__ float dppf(float x) {
    return __builtin_bit_cast(float,
        __builtin_amdgcn_update_dpp(0, __builtin_bit_cast(int, x),
                                    CTRL, 0xf, 0xf, true));
}
// max over each 32-lane half (all lanes get result); off critical path only.
#define RED32_MAX(v) do { v = fmaxf(v, dppf<0xB1>(v));                      \
                          v = fmaxf(v, dppf<0x4E>(v));                      \
                          v = fmaxf(v, dppf<0x141>(v));                     \
                          v = fmaxf(v, dppf<0x140>(v));                     \
                          v = fmaxf(v, __shfl_xor(v, 16)); } while (0)

// ---------------------------------------------------------------- chain macro
#define CHAIN(ff_, SBUF, DOPOLL, DOPUB) do {                                \
    const int ff = (ff_);                                                   \
    /* off-path: j=2..15 terms (register history) + partial merge prep */   \
    float tj[14];                                                           \
    _Pragma("unroll")                                                       \
    for (int i = 0; i < 14; ++i)                                            \
        tj[i] = bH[i] + fmaf(SBUF[i + 1], (float)(i + 2), dgc[i]);          \
    float Mp = fmaxf(pp1.x, tj[0]);                                         \
    _Pragma("unroll")                                                       \
    for (int i = 1; i < 14; ++i) Mp = fmaxf(Mp, tj[i]);                     \
    float Sp = pp1.y * __expf(pp1.x - Mp);                                  \
    _Pragma("unroll")                                                       \
    for (int i = 0; i < 14; ++i) Sp += __expf(tj[i] - Mp);                  \
    float mxn = Ma;                                                         \
    RED32_MAX(mxn);                    /* max alpha[ff], used NEXT frame */ \
    /* on-path: u broadcast -> dot -> beta[ff] */                           \
    const float uu = Sa * __expf(Ma - mx);                                  \
    if (t < 32) ubuf[c] = uu;                                               \
    const float4 u0 = *(const float4*)&ubuf[0];                             \
    const float4 u1 = *(const float4*)&ubuf[4];                             \
    const float4 u2 = *(const float4*)&ubuf[8];                             \
    const float4 u3 = *(const float4*)&ubuf[12];                            \
    const float4 u4 = *(const float4*)&ubuf[16];                            \
    const float4 u5 = *(const float4*)&ubuf[20];                            \
    const float4 u6 = *(const float4*)&ubuf[24];                            \
    const float4 u7 = *(const float4*)&ubuf[28];                            \
    float d0 = u0.x * E[0];                                                 \
    d0 = fmaf(u0.y, E[1], d0);  d0 = fmaf(u0.z, E[2], d0);                  \
    d0 = fmaf(u0.w, E[3], d0);  d0 = fmaf(u1.x, E[4], d0);                  \
    d0 = fmaf(u1.y, E[5], d0);  d0 = fmaf(u1.z, E[6], d0);                  \
    d0 = fmaf(u1.w, E[7], d0);                                              \
    float d1 = u2.x * E[8];                                                 \
    d1 = fmaf(u2.y, E[9],  d1); d1 = fmaf(u2.z, E[10], d1);                 \
    d1 = fmaf(u2.w, E[11], d1); d1 = fmaf(u3.x, E[12], d1);                 \
    d1 = fmaf(u3.y, E[13], d1); d1 = fmaf(u3.z, E[14], d1);                 \
    d1 = fmaf(u3.w, E[15], d1);                                             \
    float d2 = u4.x * E[16];                                                \
    d2 = fmaf(u4.y, E[17], d2); d2 = fmaf(u4.z, E[18], d2);                 \
    d2 = fmaf(u4.w, E[19], d2); d2 = fmaf(u5.x, E[20], d2);                 \
    d2 = fmaf(u5.y, E[21], d2); d2 = fmaf(u5.z, E[22], d2);                 \
    d2 = fmaf(u5.w, E[23], d2);                                             \
    float d3 = u6.x * E[24];                                                \
    d3 = fmaf(u6.y, E[25], d3); d3 = fmaf(u6.z, E[26], d3);                 \
    d3 = fmaf(u6.w, E[27], d3); d3 = fmaf(u7.x, E[28], d3);                 \
    d3 = fmaf(u7.y, E[29], d3); d3 = fmaf(u7.z, E[30], d3);                 \
    d3 = fmaf(u7.w, E[31], d3);                                             \
    const float dot = (d0 + d1) + (d2 + d3);                                \
    const float bb = mx + __logf(dot);                                      \
    if (t < 32) ring[wadr] = bb;                                            \
    wadr += RSTR; if (wadr >= RWRAP) wadr -= RWRAP;                         \
    /* merge -> alpha[ff+1] */                                              \
    const float t1 = bb + SBUF[0];                                          \
    const float Man = fmaxf(Mp, t1);                                        \
    Sa = fmaf(Sp, __expf(Mp - Man), __expf(t1 - Man));                      \
    Ma = Man;                                                               \
    mx = mxn;                                                               \
    if (DOPUB) {                                                            \
        asm volatile("s_waitcnt lgkmcnt(0)" ::: "memory");                  \
        if (t == 0) cntv[3] = ff;                                           \
    }                                                                       \
    if (DOPOLL) {                                                           \
        const int Fb = ff + 3;                                              \
        if (Fb <= 508) {                                                    \
            volatile int* cw = &cntv[(Fb >> 2) % 3];                        \
            int zz = 0;                                                     \
            while (*cw < Fb && ++zz < SPIN_CAP) {}                          \
            __builtin_amdgcn_fence(__ATOMIC_ACQUIRE, "workgroup", "local"); \
        }                                                                   \
    }                                                                       \
    pp1 = pp2;                                                              \
    pp2 = part[(ff + 3) & 31][c];                                           \
    _Pragma("unroll")                                                       \
    for (int i = 13; i > 0; --i) bH[i] = bH[i - 1];                         \
    bH[0] = bb;                                                             \
    /* refill SBUF with seg col ff+3 (used at frame ff+2); clamped */       \
    _Pragma("unroll")                                                       \
    for (int i = 0; i < 15; ++i) {                                          \
        int o = offv[i];                                                    \
        o = (o < (int)c || o >= SSL) ? (int)c : o;                          \
        SBUF[i] = segB[o];                                                  \
        offv[i] += SL1;                                                     \
    }                                                                       \
} while (0)

// ------------------------------------------------------------------ lag macros
#define LLOAD(BUF) do {                                                     \
    _Pragma("unroll")                                                       \
    for (int i = 0; i < 25; ++i) {                                          \
        int o = offs[i];                                                    \
        o = (o < (int)c || o >= SSL) ? (int)c : o;                          \
        BUF[i] = segB[o];                                                   \
        offs[i] += SL1;                                                     \
    }                                                                       \
} while (0)

// per-batch beta window -> registers (28 ds_reads / batch / wave)
#define LOADBR() do {                                                       \
    _Pragma("unroll")                                                       \
    for (int k = 0; k < 28; ++k) {                                          \
        int a = rbase + k * RSTR;                                           \
        if (a >= RWRAP) a -= RWRAP;                                         \
        bR[k] = ring[a];                                                    \
    }                                                                       \
} while (0)

// bR[k], k = q + 24 - i : compile-time for BOTH halves.
//   h=0: bR[k] = beta[F-40+k] -> term j=16+i of frame F+q uses beta[ff-j]  ok
//   h=1: bR[k] = beta[F-65+k] -> term j=41+i of frame F+q uses beta[ff-j]  ok
#define LF(q_, BUF, MSK) do {                                               \
    const int ff = F + (q_);                                                \
    float tt[25];                                                           \
    _Pragma("unroll")                                                       \
    for (int i = 0; i < 25; ++i) {                                          \
        const float tv = bR[(q_) + 24 - i] + fmaf(BUF[i], jfv[i], dgv[i]);  \
        bool vld = (i < nt);                                                \
        if (MSK) vld = vld && (jlo + i <= ff + 1);                          \
        tt[i] = vld ? tv : NEGF;                                            \
    }                                                                       \
    float m = fmaxf(                                                        \
        fmaxf(fmaxf(fmaxf(tt[0],tt[1]),fmaxf(tt[2],tt[3])),                 \
              fmaxf(fmaxf(tt[4],tt[5]),fmaxf(tt[6],tt[7]))),                \
        fmaxf(fmaxf(fmaxf(tt[8],tt[9]),fmaxf(tt[10],tt[11])),               \
              fmaxf(fmaxf(tt[12],tt[13]),fmaxf(tt[14],tt[15]))));           \
    m = fmaxf(m, fmaxf(                                                     \
        fmaxf(fmaxf(tt[16],tt[17]),fmaxf(tt[18],tt[19])),                   \
        fmaxf(fmaxf(tt[20],tt[21]),fmaxf(tt[22],tt[23]))));                 \
    m = fmaxf(m, tt[24]);                                                   \
    float e_[25];                                                           \
    _Pragma("unroll")                                                       \
    for (int i = 0; i < 25; ++i) e_[i] = __expf(tt[i] - m);                 \
    const float s =                                                         \
        ((((e_[0]+e_[1])+(e_[2]+e_[3]))+((e_[4]+e_[5])+(e_[6]+e_[7])))      \
       + (((e_[8]+e_[9])+(e_[10]+e_[11]))+((e_[12]+e_[13])+(e_[14]+e_[15]))))\
      + ((((e_[16]+e_[17])+(e_[18]+e_[19]))+((e_[20]+e_[21])+(e_[22]+e_[23])))\
       + e_[24]);                                                           \
    const float m2 = __shfl_xor(m, 32);                                     \
    const float s2 = __shfl_xor(s, 32);                                     \
    const float Mw = fmaxf(m, m2);                                          \
    const float Sw = fmaf(s, __expf(m - Mw), s2 * __expf(m2 - Mw));         \
    if (h == 0) part[ff & 31][c] = make_float2(Mw, Sw);                     \
} while (0)

__launch_bounds__(256, 1)
__global__ void semicrf_fwd(const float* __restrict__ seg,
                            const float* __restrict__ trans,
                            float* __restrict__ out)
{
    const int t  = threadIdx.x;
    const int b  = blockIdx.x;
    const int c  = t & 31;
    const int h  = (t >> 5) & 1;
    const int wv = t >> 6;

    __shared__ float ring[RROWS * RSTR];        // log-beta; row (p+1)&127
    __shared__ float2 part[32][32];             // lag (M,S) partials, slot f&31
    __shared__ __align__(16) float ubuf[32];    // chain matvec broadcast
    __shared__ int cnt_s[4];                    // 0..2 lag batch done, 3 chain done

    for (int i = t; i < 32 * 32; i += 256)
        ((float2*)part)[i] = make_float2(NEGF, 0.f);
    if (t < 32) ring[t] = 0.f;                  // row 0 = beta[-1] = 0
    if (t < 4)  cnt_s[t] = -1;
    __syncthreads();                            // only barrier in the kernel

    const float* segB = seg + (size_t)b * S * S * L;
    volatile int* cntv = cnt_s;

    if (wv == 0) {
        // -------------------- chain wave (R9 exact) --------------------
        __builtin_amdgcn_s_setprio(1);
        float E[32];
#pragma unroll
        for (int i = 0; i < 32; ++i) E[i] = __expf(trans[i * 32 + c]);
        const float diag_c = trans[c * 33];
        float dgc[14];
#pragma unroll
        for (int i = 0; i < 14; ++i) dgc[i] = diag_c * (float)(i + 1);

        // beta history: bH[k] = beta[f-1-k] at start of frame f
        float bH[14];
        bH[0] = 0.f;                            // beta[-1]
#pragma unroll
        for (int i = 1; i < 14; ++i) bH[i] = NEGF;

        // seg buffers: sO serves odd frames' cols, sE even; index i <-> j = i+1
        float sO[15], sE[15];
        int offv[15];
#pragma unroll
        for (int i = 0; i < 15; ++i) {
            int o1 = 1 * SL1 - i * SLN + (int)c;   // col 1
            int o2 = 2 * SL1 - i * SLN + (int)c;   // col 2
            o1 = o1 < (int)c ? (int)c : o1;
            o2 = o2 < (int)c ? (int)c : o2;
            sO[i] = segB[o1];
            sE[i] = segB[o2];
            offv[i] = 3 * SL1 - i * SLN + (int)c;  // next load: col 3
        }

        float Ma = segB[c];                     // alpha[0] as (max,sum)
        float Sa = 1.f;
        float mx = Ma;
        RED32_MAX(mx);                          // exact normalizer for frame 0
        int wadr = RSTR + (int)c;               // beta[0] -> row 1

        // wait batch 0, prime pp1=partial(1), pp2=partial(2)
        {
            volatile int* cw = &cntv[0];
            int zz = 0;
            while (*cw < 0 && ++zz < SPIN_CAP) {}
            __builtin_amdgcn_fence(__ATOMIC_ACQUIRE, "workgroup", "local");
        }
        float2 pp1 = part[1][c];
        float2 pp2 = part[2][c];

#pragma unroll 1
        for (int f = 0; f < 508; f += 4) {
            CHAIN(f + 0, sO, false, false);
            CHAIN(f + 1, sE, true,  false);
            CHAIN(f + 2, sO, false, false);
            CHAIN(f + 3, sE, false, true);
        }
        CHAIN(508, sO, false, false);
        CHAIN(509, sE, true,  false);           // poll guard skips (512 > 508)
        CHAIN(510, sO, false, false);

        // log_z[b] = LSE_c ( Ma + log Sa ); halves duplicate -> xor <= 16
        float m = Ma + __logf(Sa);
        float ss = 1.f;
#pragma unroll
        for (int mk = 1; mk <= 16; mk <<= 1) {
            const float m2 = __shfl_xor(m, mk);
            const float s2 = __shfl_xor(ss, mk);
            const float mn = fmaxf(m, m2);
            ss = ss * __expf(m - mn) + s2 * __expf(m2 - mn);
            m  = mn;
        }
        if (t == 0) out[b] = m + __logf(ss);
    } else {
        // -------------- lag waves: j=16..40 (h=0) / 41..65-pad (h=1) --------
        const int wl  = wv - 1;                 // 0,1,2
        const int jlo = h ? 41 : 16;
        const int nt  = h ? 24 : 25;            // valid terms this half
        const int jhi = h ? 65 : 40;            // window top (incl. pad)
        const float diag_c = trans[c * 33];

        float jfv[25], dgv[25];
        int offs[25];
        const int F0 = 4 * wl;
#pragma unroll
        for (int i = 0; i < 25; ++i) {
            const int jj = jlo + i;             // pad term (h=1,i=24) masked
            jfv[i] = (float)jj;
            dgv[i] = diag_c * (float)(jj - 1);
            offs[i] = F0 * SL1 - (jj - 1) * SLN + (int)c;
        }
        // beta window base: pmin = F - jhi; row (pmin+1)&127
        int rbase = (((F0 - jhi + 1) & 127) * RSTR) + (int)c;

        float bufA[25], bufB[25], bR[28];
        int cdv = -1;
        int F = F0;
        LLOAD(bufA);                            // frame F
        LLOAD(bufB);                            // frame F+1
        while (F <= 508) {
            if (F >= 16) {
                const int need = F - 13;
                int zz = 0;
                while (cdv < need && ++zz < SPIN_CAP) {
                    __builtin_amdgcn_s_sleep(1); cdv = cntv[3];
                }
                __builtin_amdgcn_fence(__ATOMIC_ACQUIRE, "workgroup", "local");
            }
            LOADBR();                           // 28-row beta window -> regs
            if (F <= 60) {
                LF(0, bufA, 1); LLOAD(bufA);    // loads F+2
                LF(1, bufB, 1); LLOAD(bufB);    // loads F+3
                LF(2, bufA, 1);
                LF(3, bufB, 1);
            } else {
                LF(0, bufA, 0); LLOAD(bufA);
                LF(1, bufB, 0); LLOAD(bufB);
                LF(2, bufA, 0);
                LF(3, bufB, 0);
            }
            asm volatile("s_waitcnt lgkmcnt(0)" ::: "memory");
            if ((t & 63) == 0) cntv[wl] = F;
            // advance to next batch (F+12): offs currently at F+4
#pragma unroll
            for (int i = 0; i < 25; ++i) offs[i] += 8 * SL1;
            rbase += 12 * RSTR; if (rbase >= RWRAP) rbase -= RWRAP;
            F += 12;
            if (F <= 508) { LLOAD(bufA); LLOAD(bufB); }
        }
    }
}

extern "C" void kernel_launch(void* const* d_in, const int* in_sizes, int n_in,
                              void* d_out, int out_size, void* d_ws, size_t ws_size,
                              hipStream_t stream) {
    const float* seg   = (const float*)d_in[0];   // [8, 512, 512, 32] fp32
    const float* trans = (const float*)d_in[1];   // [32, 32] fp32
    float* out = (float*)d_out;                   // [8] fp32
    hipLaunchKernelGGL(semicrf_fwd, dim3(8), dim3(256), 0, stream,
                       seg, trans, out);
}